// Round 3
// baseline (1666.525 us; speedup 1.0000x reference)
//
#include <hip/hip_runtime.h>
#include <stdint.h>

#define N_SIZE 4096
#define N_STEPS 512
#define WROW 8192
#define THRESH 10.0f

#define NWG 16                 // workgroups in distributed scan
#define NPW (N_SIZE / NWG)     // 256 neurons per WG
#define WST_BYTES ((size_t)N_SIZE * N_SIZE * 4)
#define SC_UINTS 1024          // stamp|cnt words, padded: [par][w] at par*512+w*32
#define SEG_INTS (2 * NWG * NPW)

#define F4E(v, j) ((j) == 0 ? (v).x : (j) == 1 ? (v).y : (j) == 2 ? (v).z : (v).w)

// ---------------- transpose: WsT[s][o] = W[o*8192 + 4096 + s] ----------------
__global__ __launch_bounds__(256) void k_transpose(const float* __restrict__ W,
                                                   float* __restrict__ WsT) {
    __shared__ float tile[32][33];
    const int bs = blockIdx.x * 32;
    const int bo = blockIdx.y * 32;
    const int tx = threadIdx.x;
    const int ty = threadIdx.y;
#pragma unroll
    for (int j = 0; j < 4; ++j)
        tile[ty + j * 8][tx] = W[(size_t)(bo + ty + j * 8) * WROW + N_SIZE + bs + tx];
    __syncthreads();
#pragma unroll
    for (int j = 0; j < 4; ++j)
        WsT[(size_t)(bs + ty + j * 8) * N_SIZE + bo + tx] = tile[tx][ty + j * 8];
}

// ---------------- GEMM: C[t][o] = sum_k x[t][k] * W[o][k], split-K=2 --------
#define BM 64
#define BN 128
#define BK 16
#define KHALF (N_SIZE / 2)
#define ALD 68
#define BLD 132

__global__ __launch_bounds__(128) void k_gemm(const float* __restrict__ x,
                                              const float* __restrict__ W,
                                              float* __restrict__ dst0,
                                              float* __restrict__ dst1) {
    __shared__ float As[BK][ALD];
    __shared__ float Bs[BK][BLD];
    const int tid = threadIdx.x;
    const int bm = blockIdx.y * BM;
    const int bn = blockIdx.x * BN;
    const int kb0 = blockIdx.z * KHALF;
    float* dst = blockIdx.z ? dst1 : dst0;

    const int m0 = (tid >> 4) << 3;
    const int n0 = (tid & 15) << 2;
    const int ar = tid >> 2;
    const int ac = (tid & 3) << 2;
    const float* Ap = &x[(size_t)(bm + ar) * N_SIZE + kb0 + ac];
    const float* Bp = &W[(size_t)(bn + ar) * WROW + kb0 + ac];

    float4 pa0 = *(const float4*)&Ap[0];
    float4 pa1 = *(const float4*)&Ap[(size_t)32 * N_SIZE];
    float4 pb0 = *(const float4*)&Bp[0];
    float4 pb1 = *(const float4*)&Bp[(size_t)32 * WROW];
    float4 pb2 = *(const float4*)&Bp[(size_t)64 * WROW];
    float4 pb3 = *(const float4*)&Bp[(size_t)96 * WROW];

    float acc[8][8];
#pragma unroll
    for (int i = 0; i < 8; ++i)
#pragma unroll
        for (int j = 0; j < 8; ++j) acc[i][j] = 0.f;

    const int nkt = KHALF / BK;
    for (int kt = 0; kt < nkt; ++kt) {
        __syncthreads();
#pragma unroll
        for (int j = 0; j < 4; ++j) {
            As[ac + j][ar]      = F4E(pa0, j);
            As[ac + j][ar + 32] = F4E(pa1, j);
            Bs[ac + j][ar]      = F4E(pb0, j);
            Bs[ac + j][ar + 32] = F4E(pb1, j);
            Bs[ac + j][ar + 64] = F4E(pb2, j);
            Bs[ac + j][ar + 96] = F4E(pb3, j);
        }
        __syncthreads();
        if (kt + 1 < nkt) {
            const float* Ap2 = Ap + (size_t)(kt + 1) * BK;
            const float* Bp2 = Bp + (size_t)(kt + 1) * BK;
            pa0 = *(const float4*)&Ap2[0];
            pa1 = *(const float4*)&Ap2[(size_t)32 * N_SIZE];
            pb0 = *(const float4*)&Bp2[0];
            pb1 = *(const float4*)&Bp2[(size_t)32 * WROW];
            pb2 = *(const float4*)&Bp2[(size_t)64 * WROW];
            pb3 = *(const float4*)&Bp2[(size_t)96 * WROW];
        }
#pragma unroll
        for (int k = 0; k < BK; ++k) {
            const float4 a0 = *(const float4*)&As[k][m0];
            const float4 a1 = *(const float4*)&As[k][m0 + 4];
            const float4 b0 = *(const float4*)&Bs[k][n0];
            const float4 b1 = *(const float4*)&Bs[k][n0 + 64];
            const float av[8] = {a0.x, a0.y, a0.z, a0.w, a1.x, a1.y, a1.z, a1.w};
            const float bv[8] = {b0.x, b0.y, b0.z, b0.w, b1.x, b1.y, b1.z, b1.w};
#pragma unroll
            for (int i = 0; i < 8; ++i)
#pragma unroll
                for (int j = 0; j < 8; ++j)
                    acc[i][j] = fmaf(av[i], bv[j], acc[i][j]);
        }
    }
#pragma unroll
    for (int i = 0; i < 8; ++i) {
        float* cp = &dst[(size_t)(bm + m0 + i) * N_SIZE + bn];
        const float4 o0 = {acc[i][0], acc[i][1], acc[i][2], acc[i][3]};
        const float4 o1 = {acc[i][4], acc[i][5], acc[i][6], acc[i][7]};
        *(float4*)&cp[n0] = o0;
        *(float4*)&cp[n0 + 64] = o1;
    }
}

__global__ __launch_bounds__(256) void k_reduce(float* __restrict__ acc,
                                                const float* __restrict__ part) {
    const size_t i = ((size_t)blockIdx.x * 256 + threadIdx.x) * 4;
    const float4 a = *(const float4*)&acc[i];
    const float4 b = *(const float4*)&part[i];
    const float4 r = {a.x + b.x, a.y + b.y, a.z + b.z, a.w + b.w};
    *(float4*)&acc[i] = r;
}

// ---------------- init: zero stamp|cnt words (every launch, replay-safe) ----
__global__ __launch_bounds__(256) void k_init(uint32_t* __restrict__ sc) {
#pragma unroll
    for (int j = 0; j < SC_UINTS / 256; ++j)
        sc[j * 256 + threadIdx.x] = 0;
}

// ---------------- distributed scan: NWG WGs x 1 wave, flag-synced ----------
// WG w owns neurons [w*NPW, (w+1)*NPW). Per step: poll 16 stamp words
// (parity-double-buffered), stage concatenated spike list to LDS, gather own
// WsT slice (L2-resident, 1 KB/column), update mem, publish own sorted spike
// segment + release stamp. Sum order = globally ascending neuron index.
__global__ __launch_bounds__(64) void k_scan_mw(const float* __restrict__ WsT,
                                                float* __restrict__ spk_out,
                                                float* __restrict__ mem_out,
                                                uint32_t* __restrict__ sc,
                                                int* __restrict__ segs) {
    __shared__ int list[N_SIZE];
    __shared__ int cnts[NWG];
    const int w = blockIdx.x;
    const int lane = threadIdx.x;                 // 0..63
    const int cb = w * NPW + (lane << 2);         // this thread's 4 neurons
    const unsigned long long below = (lane == 0) ? 0ULL : (~0ULL >> (64 - lane));

    float4 mem = {0.f, 0.f, 0.f, 0.f};
    float4 cn = *(const float4*)&mem_out[cb];     // cur_x row 0 slice

    for (int t = 0; t < N_STEPS; ++t) {
        float4 c = cn;

        // ---- acquire other WGs' spike segments for this step ----
        int cnt = 0;
        if (t > 0) {
            const int par = t & 1;
            if (lane < NWG) {
                uint32_t v;
                for (;;) {
                    v = __hip_atomic_load(&sc[par * 512 + lane * 32],
                                          __ATOMIC_ACQUIRE, __HIP_MEMORY_SCOPE_AGENT);
                    if ((v >> 16) >= (uint32_t)t) break;
                    __builtin_amdgcn_s_sleep(1);
                }
                cnts[lane] = (int)(v & 0xffffu);
            }
            __syncthreads();
            int off[NWG];
            int tot = 0;
#pragma unroll
            for (int u = 0; u < NWG; ++u) { off[u] = tot; tot += cnts[u]; }
            // stage concatenated index list: thread p fetches flat entry p
            for (int p = lane; p < tot; p += 64) {
                int u = 0, o = 0;
#pragma unroll
                for (int q = 0; q < NWG; ++q)
                    if (p >= off[q]) { u = q; o = off[q]; }
                const int id = __hip_atomic_load(&segs[(par * NWG + u) * NPW + (p - o)],
                                                 __ATOMIC_RELAXED, __HIP_MEMORY_SCOPE_AGENT);
                list[p] = id;
            }
            __syncthreads();
            cnt = tot;
        }

        // ---- gather: 8-wide batched column slices (plain loads, L2-hot) ----
        for (int i = 0; i < cnt; i += 8) {
            int sx[8];
            float fx[8];
#pragma unroll
            for (int j = 0; j < 8; ++j) {
                const bool vld = (i + j < cnt);
                sx[j] = vld ? list[i + j] : list[i];
                fx[j] = vld ? 1.f : 0.f;
            }
            float4 wv[8];
#pragma unroll
            for (int j = 0; j < 8; ++j)
                wv[j] = *(const float4*)&WsT[(size_t)sx[j] * N_SIZE + cb];
#pragma unroll
            for (int j = 0; j < 8; ++j) {
                c.x = fmaf(fx[j], wv[j].x, c.x);
                c.y = fmaf(fx[j], wv[j].y, c.y);
                c.z = fmaf(fx[j], wv[j].z, c.z);
                c.w = fmaf(fx[j], wv[j].w, c.w);
            }
        }

        // ---- membrane update, threshold, spike ----
        mem.x += c.x; mem.y += c.y; mem.z += c.z; mem.w += c.w;
        const bool s0 = mem.x > THRESH, s1 = mem.y > THRESH;
        const bool s2 = mem.z > THRESH, s3 = mem.w > THRESH;
        mem.x -= s0 ? THRESH : 0.f;  mem.y -= s1 ? THRESH : 0.f;
        mem.z -= s2 ? THRESH : 0.f;  mem.w -= s3 ? THRESH : 0.f;

        // ---- publish own sorted segment + release stamp|cnt ----
        const unsigned long long B0 = __ballot(s0), B1 = __ballot(s1);
        const unsigned long long B2 = __ballot(s2), B3 = __ballot(s3);
        const int pre = __popcll(B0 & below) + __popcll(B1 & below) +
                        __popcll(B2 & below) + __popcll(B3 & below);
        const int total = __popcll(B0) + __popcll(B1) + __popcll(B2) + __popcll(B3);
        if (t + 1 < N_STEPS) {
            const int par2 = (t + 1) & 1;
            int* myseg = &segs[(par2 * NWG + w) * NPW];
            int o2 = pre;
            if (s0) __hip_atomic_store(&myseg[o2++], cb + 0, __ATOMIC_RELAXED, __HIP_MEMORY_SCOPE_AGENT);
            if (s1) __hip_atomic_store(&myseg[o2++], cb + 1, __ATOMIC_RELAXED, __HIP_MEMORY_SCOPE_AGENT);
            if (s2) __hip_atomic_store(&myseg[o2++], cb + 2, __ATOMIC_RELAXED, __HIP_MEMORY_SCOPE_AGENT);
            if (s3) __hip_atomic_store(&myseg[o2++], cb + 3, __ATOMIC_RELAXED, __HIP_MEMORY_SCOPE_AGENT);
            if (lane == 0)
                __hip_atomic_store(&sc[par2 * 512 + w * 32],
                                   ((uint32_t)(t + 1) << 16) | (uint32_t)total,
                                   __ATOMIC_RELEASE, __HIP_MEMORY_SCOPE_AGENT);
        }

        // ---- off-critical-path: outputs + next-row prefetch ----
        const float4 sp = {s0 ? 1.f : 0.f, s1 ? 1.f : 0.f,
                           s2 ? 1.f : 0.f, s3 ? 1.f : 0.f};
        *(float4*)&spk_out[(size_t)t * N_SIZE + cb] = sp;
        *(float4*)&mem_out[(size_t)t * N_SIZE + cb] = mem;
        const int tn = (t + 1 < N_STEPS) ? (t + 1) : t;
        cn = *(const float4*)&mem_out[(size_t)tn * N_SIZE + cb];
    }
}

// ---------------- fallback: proven single-WG scan ----------------
template <int USE_WST>
__global__ __launch_bounds__(1024) void k_scan1(const float* __restrict__ WsT,
                                                const float* __restrict__ W,
                                                float* __restrict__ spk_out,
                                                float* __restrict__ mem_out) {
    __shared__ int lists[2][N_SIZE];
    __shared__ int wcnt[16];
    const int tid = threadIdx.x;
    const int wave = tid >> 6;
    const int lane = tid & 63;
    const int base = tid << 2;
    const unsigned long long below = (lane == 0) ? 0ULL : (~0ULL >> (64 - lane));

    float4 mem = {0.f, 0.f, 0.f, 0.f};
    int cnt = 0, cur = 0;
    for (int t = 0; t < N_STEPS; ++t) {
        float* mrow = &mem_out[(size_t)t * N_SIZE + base];
        float4 c = *(const float4*)mrow;
        const int* lst = lists[cur];
        for (int i = 0; i < cnt; ++i) {
            const int s = lst[i];
            float4 w0;
            if (USE_WST) {
                w0 = *(const float4*)&WsT[(size_t)s * N_SIZE + base];
            } else {
                w0.x = W[(size_t)(base + 0) * WROW + N_SIZE + s];
                w0.y = W[(size_t)(base + 1) * WROW + N_SIZE + s];
                w0.z = W[(size_t)(base + 2) * WROW + N_SIZE + s];
                w0.w = W[(size_t)(base + 3) * WROW + N_SIZE + s];
            }
            c.x += w0.x; c.y += w0.y; c.z += w0.z; c.w += w0.w;
        }
        mem.x += c.x; mem.y += c.y; mem.z += c.z; mem.w += c.w;
        const bool s0 = mem.x > THRESH, s1 = mem.y > THRESH;
        const bool s2 = mem.z > THRESH, s3 = mem.w > THRESH;
        mem.x -= s0 ? THRESH : 0.f;  mem.y -= s1 ? THRESH : 0.f;
        mem.z -= s2 ? THRESH : 0.f;  mem.w -= s3 ? THRESH : 0.f;
        const float4 spkv = {s0 ? 1.f : 0.f, s1 ? 1.f : 0.f,
                             s2 ? 1.f : 0.f, s3 ? 1.f : 0.f};
        *(float4*)&spk_out[(size_t)t * N_SIZE + base] = spkv;
        *(float4*)mrow = mem;
        const unsigned long long b0 = __ballot(s0), b1 = __ballot(s1);
        const unsigned long long b2 = __ballot(s2), b3 = __ballot(s3);
        const int pre = __popcll(b0 & below) + __popcll(b1 & below) +
                        __popcll(b2 & below) + __popcll(b3 & below);
        if (lane == 0)
            wcnt[wave] = __popcll(b0) + __popcll(b1) + __popcll(b2) + __popcll(b3);
        __syncthreads();
        int woff = 0, total = 0;
#pragma unroll
        for (int wv = 0; wv < 16; ++wv) {
            const int cw = wcnt[wv];
            if (wv < wave) woff += cw;
            total += cw;
        }
        int* nxt = lists[cur ^ 1];
        int off = woff + pre;
        if (s0) nxt[off++] = base;
        if (s1) nxt[off++] = base + 1;
        if (s2) nxt[off++] = base + 2;
        if (s3) nxt[off++] = base + 3;
        __syncthreads();
        cnt = total;
        cur ^= 1;
    }
}

extern "C" void kernel_launch(void* const* d_in, const int* in_sizes, int n_in,
                              void* d_out, int out_size, void* d_ws, size_t ws_size,
                              hipStream_t stream) {
    const float* x = (const float*)d_in[0];
    const float* W = (const float*)d_in[1];
    float* spk_out = (float*)d_out;
    float* mem_out = spk_out + (size_t)N_STEPS * N_SIZE;
    float* WsT = (float*)d_ws;
    uint32_t* sc = (uint32_t*)((char*)d_ws + WST_BYTES);
    int* segs = (int*)((char*)d_ws + WST_BYTES + SC_UINTS * 4);
    const bool use_wst = ws_size >= WST_BYTES;
    const bool mw = ws_size >= WST_BYTES + SC_UINTS * 4 + SEG_INTS * 4;

    if (use_wst)
        k_transpose<<<dim3(N_SIZE / 32, N_SIZE / 32), dim3(32, 8), 0, stream>>>(W, WsT);

    k_gemm<<<dim3(N_SIZE / BN, N_STEPS / BM, 2), 128, 0, stream>>>(x, W, mem_out, spk_out);
    k_reduce<<<(N_STEPS * N_SIZE) / (256 * 4), 256, 0, stream>>>(mem_out, spk_out);

    if (mw) {
        k_init<<<1, 256, 0, stream>>>(sc);
        k_scan_mw<<<NWG, 64, 0, stream>>>(WsT, spk_out, mem_out, sc, segs);
    } else if (use_wst) {
        k_scan1<1><<<1, 1024, 0, stream>>>(WsT, W, spk_out, mem_out);
    } else {
        k_scan1<0><<<1, 1024, 0, stream>>>(WsT, W, spk_out, mem_out);
    }
}